// Round 5
// baseline (51730.615 us; speedup 1.0000x reference)
//
#include <hip/hip_runtime.h>
#include <hip/hip_cooperative_groups.h>
#include <cstdint>
#include <cstddef>

namespace cg = cooperative_groups;

static constexpr int BATCH   = 128;
static constexpr int TSTEPS  = 512;
static constexpr int NBLOCKS = 244;   // compute blocks
static constexpr int NGRID   = NBLOCKS + 1;  // + 1 barrier-master block; <= 256 CUs
static constexpr int NT      = 256;
static constexpr int CK      = 64;    // k-rows per staged chunk (32 KB)
static constexpr int NBAR    = TSTEPS + 3;   // barriers per scan

// block role ranges
static constexpr int NB1 = 80, NB2 = 100, NB3 = 32, NB4 = 32;
static constexpr int RB2 = NB1, RB3 = NB1 + NB2, RB4 = NB1 + NB2 + NB3;

// ---------------- workspace layout (float offsets) ----------------
static constexpr size_t O_XT  = 0;                         // [512][64][128]
static constexpr size_t SZ_XT = 512ull * 64 * 128;
static constexpr size_t O_H1  = O_XT + SZ_XT;              // 2 parities x [H][128]
static constexpr size_t O_H2  = O_H1 + 2ull * 640 * 128;
static constexpr size_t O_H3  = O_H2 + 2ull * 400 * 128;
static constexpr size_t O_H4  = O_H3 + 2ull * 256 * 128;
static constexpr size_t O_HEND= O_H4 + 2ull * 256 * 128;
static constexpr size_t HTOT  = O_HEND - O_H1;
static constexpr size_t O_PK1 = O_HEND;                    // [80][704][8][4]
static constexpr size_t O_PK2 = O_PK1 + 80ull  * 704  * 8 * 4;   // [100][1040][4][4]
static constexpr size_t O_PK3 = O_PK2 + 100ull * 1040 * 4 * 4;   // [32][656][8][4]
static constexpr size_t O_PK4 = O_PK3 + 32ull  * 656  * 8 * 4;   // [32][512][8][4]
static constexpr size_t O_CTR = O_PK4 + 32ull  * 512  * 8 * 4;   // 2048 uints (8 KB)
// barrier area (uint offsets from U = ws+O_CTR):
//   slots[0..255]   : per-block arrival values
//   U[256 + g*64]   : release lines, g = 0..15 (spread 256 B apart)

struct KParams {
  const float *x;
  const float *k1, *r1, *b1, *k2, *r2, *b2, *k3, *r3, *b3, *k4, *r4, *b4;
  const float *wd1, *bd1, *wd2, *bd2, *wd3, *bd3, *wd4, *bd4, *wd5, *bd5, *wd6, *bd6;
  float *out;
  float *ws;
};

__device__ __forceinline__ void fma4(float4& a, float s, const float4& w) {
  a.x += s * w.x; a.y += s * w.y; a.z += s * w.z; a.w += s * w.w;
}
__device__ __forceinline__ float sigm(float v) { return 1.f / (1.f + expf(-v)); }

// ---- coherent (agent-scope) h exchange ----
__device__ __forceinline__ void h_store2(float* p, float a, float b) {
  union { float f[2]; unsigned long long u; } v; v.f[0] = a; v.f[1] = b;
  __hip_atomic_store((unsigned long long*)p, v.u, __ATOMIC_RELAXED, __HIP_MEMORY_SCOPE_AGENT);
}
__device__ __forceinline__ unsigned long long h_load8(const float* p) {
  return __hip_atomic_load((const unsigned long long*)p, __ATOMIC_RELAXED, __HIP_MEMORY_SCOPE_AGENT);
}
__device__ __forceinline__ float h_load1(const float* p) {
  return __hip_atomic_load(p, __ATOMIC_RELAXED, __HIP_MEMORY_SCOPE_AGENT);
}
__device__ __forceinline__ unsigned u_load(const unsigned* p) {
  return __hip_atomic_load(p, __ATOMIC_RELAXED, __HIP_MEMORY_SCOPE_AGENT);
}
__device__ __forceinline__ void u_store(unsigned* p, unsigned v) {
  __hip_atomic_store(p, v, __ATOMIC_RELAXED, __HIP_MEMORY_SCOPE_AGENT);
}

// ---- distributed barrier: slot store + master scan + spread release lines ----
// Compute-block side: no RMW, no shared-line polling storm.
__device__ __forceinline__ void light_barrier(unsigned* U, int bid, unsigned s1) {
  asm volatile("s_waitcnt vmcnt(0)" ::: "memory");  // h sc1-stores reached coherence pt
  __syncthreads();
  if (threadIdx.x == 0) {
    u_store(&U[bid], s1);                           // arrival (posted store)
    const unsigned* rel = &U[256 + (bid & 15) * 64];
    while (u_load(rel) < s1) __builtin_amdgcn_s_sleep(2);
  }
  __syncthreads();
}

// Master block: one thread per slot, wide AND-detect, then fan-out release.
__device__ void master_role(unsigned* U) {
  const int tid = threadIdx.x;
  for (unsigned s1 = 1; s1 <= (unsigned)NBAR; ++s1) {
    for (;;) {
      unsigned v = (tid < NBLOCKS) ? u_load(&U[tid]) : 0xFFFFFFFFu;
      if (__syncthreads_and((int)(v >= s1))) break;
      __builtin_amdgcn_s_sleep(2);
    }
    if (tid < 16) u_store(&U[256 + tid * 64], s1);
  }
}

// ---------------- weight prepack: pack[blk][k][quad][gate] ----------------
__device__ void prepack_layer(const float* __restrict__ gk, const float* __restrict__ gr,
                              float* __restrict__ pack, int DIN, int H, int NJ, int NBLK,
                              int gtid, int gstr) {
  const long K = DIN + H;
  const long total = (long)NBLK * K * NJ * 4;
  for (long e = gtid; e < total; e += gstr) {
    int  g   = (int)(e & 3);
    long r   = e >> 2;
    int  q   = (int)(r % NJ);
    long r2  = r / NJ;
    int  k   = (int)(r2 % K);
    int  blk = (int)(r2 / K);
    int  j   = blk * NJ + q;
    float v = (k < DIN) ? gk[(size_t)k * 4 * H + (size_t)g * H + j]
                        : gr[(size_t)(k - DIN) * 4 * H + (size_t)g * H + j];
    pack[e] = v;
  }
}

// ---------------- persistent LSTM layer role (chunked LDS pipeline) ----------------
template<int DIN, int H, int NJ, int BG, int LOFF, bool SEQIN>
__device__ __forceinline__ void lstm_role(int blk, int bid,
                          const float* __restrict__ xT,
                          const float* __restrict__ inH,
                          float* __restrict__ ownH,
                          const float* __restrict__ pack,
                          const float* __restrict__ gbias,
                          float* lds, unsigned* U) {
  constexpr int K   = DIN + H;
  constexpr int MB  = BATCH / BG;                 // 4 or 2
  constexpr int NCH = (K + CK - 1) / CK;
  constexpr int PPT = (CK * 64) / NT;             // 16 8-byte pairs / thread / chunk
  static_assert(NJ * BG == NT, "bad split");

  const int tid = threadIdx.x;
  const int jj  = tid / BG;
  const int bg  = tid % BG;
  const int b0  = bg * MB;
  const int j   = blk * NJ + jj;

  const float* mypack = pack + (size_t)blk * K * NJ * 4;
  const float4 bias = make_float4(gbias[j], gbias[H + j], gbias[2 * H + j], gbias[3 * H + j]);

  float c[MB];
  #pragma unroll
  for (int m = 0; m < MB; ++m) c[m] = 0.f;

  float* buf0 = lds;
  float* buf1 = lds + CK * BATCH;

  for (int s = 0; s < NBAR; ++s) {
    const int t = s - LOFF;
    if (t >= 0 && t < TSTEPS) {
      const int par = (s - 1) & 1;
      const float* src_lo = SEQIN ? (xT + (size_t)t * DIN * BATCH)
                                  : (inH + (size_t)par * DIN * BATCH);
      const float* src_hi = ownH + (size_t)par * H * BATCH;

      float4 a[MB];
      #pragma unroll
      for (int m = 0; m < MB; ++m) a[m] = make_float4(0.f, 0.f, 0.f, 0.f);

      // ---- stage chunk 0 (burst: all loads issued before any use) ----
      unsigned long long tmp[PPT];
      #pragma unroll
      for (int r = 0; r < PPT; ++r) {
        const int p  = r * NT + tid;
        const int k  = p >> 6;
        const int bb = (p & 63) * 2;
        const float* sp = (k < DIN) ? (src_lo + (size_t)k * BATCH + bb)
                                    : (src_hi + (size_t)(k - DIN) * BATCH + bb);
        tmp[r] = h_load8(sp);
      }
      #pragma unroll
      for (int r = 0; r < PPT; ++r) {
        const int p = r * NT + tid;
        *(unsigned long long*)(buf0 + 2 * p) = tmp[r];
      }
      __syncthreads();

      for (int ch = 0; ch < NCH; ++ch) {
        float* cur = (ch & 1) ? buf1 : buf0;
        float* nxt = (ch & 1) ? buf0 : buf1;
        const int kb = ch * CK;
        const bool more = (ch + 1 < NCH);

        if (more) {
          const int kb2 = kb + CK;
          #pragma unroll
          for (int r = 0; r < PPT; ++r) {
            const int p  = r * NT + tid;
            const int k  = kb2 + (p >> 6);
            const int bb = (p & 63) * 2;
            if (k < K) {
              const float* sp = (k < DIN) ? (src_lo + (size_t)k * BATCH + bb)
                                          : (src_hi + (size_t)(k - DIN) * BATCH + bb);
              tmp[r] = h_load8(sp);
            } else tmp[r] = 0ull;
          }
        }

        const int kmax = (K - kb < CK) ? (K - kb) : CK;
        const float* wrow = mypack + ((size_t)kb * NJ + jj) * 4;
        #pragma unroll 4
        for (int kl = 0; kl < kmax; ++kl) {
          float4 w = *(const float4*)(wrow + (size_t)kl * NJ * 4);
          if constexpr (MB == 4) {
            float4 hv = *(const float4*)(cur + kl * BATCH + b0);
            fma4(a[0], hv.x, w); fma4(a[1], hv.y, w);
            fma4(a[2], hv.z, w); fma4(a[3], hv.w, w);
          } else {
            float2 hv = *(const float2*)(cur + kl * BATCH + b0);
            fma4(a[0], hv.x, w); fma4(a[1], hv.y, w);
          }
        }

        if (more) {
          #pragma unroll
          for (int r = 0; r < PPT; ++r) {
            const int p = r * NT + tid;
            *(unsigned long long*)(nxt + 2 * p) = tmp[r];
          }
        }
        __syncthreads();
      }

      // ---- epilogue: gates, state update, coherent store ----
      float* dst = ownH + (size_t)(s & 1) * H * BATCH + (size_t)j * BATCH + b0;
      float hv[MB];
      #pragma unroll
      for (int m = 0; m < MB; ++m) {
        float ig = sigm(a[m].x + bias.x);
        float fg = sigm(a[m].y + bias.y);
        float gg = tanhf(a[m].z + bias.z);
        float og = sigm(a[m].w + bias.w);
        c[m] = fg * c[m] + ig * gg;
        hv[m] = og * tanhf(c[m]);
      }
      if constexpr (MB == 4) {
        h_store2(dst + 0, hv[0], hv[1]);
        h_store2(dst + 2, hv[2], hv[3]);
      } else {
        h_store2(dst, hv[0], hv[1]);
      }
    }
    light_barrier(U, bid, (unsigned)(s + 1));
  }
}

// ---------------- dense head helpers ----------------
__device__ void dense_stage(const float* in, float* outb,
                            const float* __restrict__ w, const float* __restrict__ bias,
                            int din, int dout, bool relu) {
  for (int jc = threadIdx.x; jc < dout; jc += NT) {
    float s = bias[jc];
    for (int d = 0; d < din; ++d) s += in[d] * w[(size_t)d * dout + jc];
    outb[jc] = relu ? fmaxf(s, 0.f) : s;
  }
  __syncthreads();
}

// ---------------- the fused cooperative kernel ----------------
__global__ __launch_bounds__(NT, 1) void fused_kernel(KParams p) {
  cg::grid_group grid = cg::this_grid();
  __shared__ float lds[2 * CK * BATCH];   // 64 KB

  float* ws  = p.ws;
  unsigned* U = (unsigned*)(ws + O_CTR);
  const int tid  = threadIdx.x;
  const int bid  = blockIdx.x;
  const int gtid = bid * NT + tid;
  const int gstr = NGRID * NT;

  // ---- phase 0a: zero all h parity buffers ----
  {
    float* hb = ws + O_H1;
    for (size_t i = gtid; i < HTOT; i += gstr) hb[i] = 0.f;
  }
  // ---- phase 0b: prepack weights ----
  prepack_layer(p.k1, p.r1, ws + O_PK1, 64,  640, 8, NB1, gtid, gstr);
  prepack_layer(p.k2, p.r2, ws + O_PK2, 640, 400, 4, NB2, gtid, gstr);
  prepack_layer(p.k3, p.r3, ws + O_PK3, 400, 256, 8, NB3, gtid, gstr);
  prepack_layer(p.k4, p.r4, ws + O_PK4, 256, 256, 8, NB4, gtid, gstr);
  // ---- phase 0c: transpose x [128][512][64] -> xT [512][64][128] ----
  {
    float* tile = lds;                  // [64][129] padded = 33 KB
    float* xT   = ws + O_XT;
    for (int t = bid; t < TSTEPS; t += NGRID) {
      int b = tid >> 1, dbase = (tid & 1) * 32;
      const float* src = p.x + ((size_t)b * TSTEPS + t) * 64 + dbase;
      #pragma unroll
      for (int q = 0; q < 8; ++q) {
        float4 v = *(const float4*)(src + 4 * q);
        tile[(dbase + 4 * q + 0) * 129 + b] = v.x;
        tile[(dbase + 4 * q + 1) * 129 + b] = v.y;
        tile[(dbase + 4 * q + 2) * 129 + b] = v.z;
        tile[(dbase + 4 * q + 3) * 129 + b] = v.w;
      }
      __syncthreads();
      int d = tid >> 2, bb = (tid & 3) * 32;
      float* dst = xT + ((size_t)t * 64 + d) * BATCH + bb;
      #pragma unroll
      for (int q = 0; q < 8; ++q) {
        float4 v = make_float4(tile[d * 129 + bb + 4 * q + 0],
                               tile[d * 129 + bb + 4 * q + 1],
                               tile[d * 129 + bb + 4 * q + 2],
                               tile[d * 129 + bb + 4 * q + 3]);
        *(float4*)(dst + 4 * q) = v;
      }
      __syncthreads();
    }
  }

  // ONE full CG sync: publishes xT/packs/zeroed-h everywhere
  grid.sync();

  // ---- phase 1: pipelined 4-layer LSTM scan ----
  if (bid == NBLOCKS) {
    master_role(U);                     // dedicated barrier master
  } else if (bid < RB2) {
    lstm_role< 64, 640, 8, 32, 0, true >(bid,       bid, ws + O_XT, nullptr,   ws + O_H1, ws + O_PK1, p.b1, lds, U);
  } else if (bid < RB3) {
    lstm_role<640, 400, 4, 64, 1, false>(bid - RB2, bid, nullptr,  ws + O_H1, ws + O_H2, ws + O_PK2, p.b2, lds, U);
  } else if (bid < RB4) {
    lstm_role<400, 256, 8, 32, 2, false>(bid - RB3, bid, nullptr,  ws + O_H2, ws + O_H3, ws + O_PK3, p.b3, lds, U);
  } else {
    lstm_role<256, 256, 8, 32, 3, false>(bid - RB4, bid, nullptr,  ws + O_H3, ws + O_H4, ws + O_PK4, p.b4, lds, U);
  }

  // ---- phase 2: dense head (h4 final is parity 0; read agent-scope) ----
  if (bid < BATCH) {
    const int b = bid;
    float* A = lds;
    float* B = lds + 512;
    const float* h4 = ws + O_H4;
    for (int d = tid; d < 256; d += NT) A[d] = h_load1(h4 + (size_t)d * BATCH + b);
    __syncthreads();
    dense_stage(A, B, p.wd1, p.bd1, 256, 512, true);
    dense_stage(B, A, p.wd2, p.bd2, 512, 256, true);
    dense_stage(A, B, p.wd3, p.bd3, 256, 128, true);
    dense_stage(B, A, p.wd4, p.bd4, 128, 64,  true);
    dense_stage(A, B, p.wd5, p.bd5, 64,  16,  true);
    dense_stage(B, A, p.wd6, p.bd6, 16,  3,   false);
    if (tid == 0) {
      float z0 = A[0], z1 = A[1], z2 = A[2];
      float m  = fmaxf(fmaxf(z0, z1), z2);
      float e0 = expf(z0 - m), e1 = expf(z1 - m), e2 = expf(z2 - m);
      float s  = e0 + e1 + e2;
      p.out[b * 3 + 0] = e0 / s;
      p.out[b * 3 + 1] = e1 / s;
      p.out[b * 3 + 2] = e2 / s;
    }
  }
}

// ---------------- launch ----------------
extern "C" void kernel_launch(void* const* d_in, const int* in_sizes, int n_in,
                              void* d_out, int out_size, void* d_ws, size_t ws_size,
                              hipStream_t stream) {
  KParams prm;
  prm.x  = (const float*)d_in[0];
  prm.k1 = (const float*)d_in[1];  prm.r1 = (const float*)d_in[2];  prm.b1 = (const float*)d_in[3];
  prm.k2 = (const float*)d_in[4];  prm.r2 = (const float*)d_in[5];  prm.b2 = (const float*)d_in[6];
  prm.k3 = (const float*)d_in[7];  prm.r3 = (const float*)d_in[8];  prm.b3 = (const float*)d_in[9];
  prm.k4 = (const float*)d_in[10]; prm.r4 = (const float*)d_in[11]; prm.b4 = (const float*)d_in[12];
  prm.wd1 = (const float*)d_in[13]; prm.bd1 = (const float*)d_in[14];
  prm.wd2 = (const float*)d_in[15]; prm.bd2 = (const float*)d_in[16];
  prm.wd3 = (const float*)d_in[17]; prm.bd3 = (const float*)d_in[18];
  prm.wd4 = (const float*)d_in[19]; prm.bd4 = (const float*)d_in[20];
  prm.wd5 = (const float*)d_in[21]; prm.bd5 = (const float*)d_in[22];
  prm.wd6 = (const float*)d_in[23]; prm.bd6 = (const float*)d_in[24];
  prm.out = (float*)d_out;
  prm.ws  = (float*)d_ws;

  // zero barrier slots + release lines (ws is poisoned 0xAA before every launch)
  hipMemsetAsync((char*)d_ws + O_CTR * 4, 0, 8192, stream);

  void* args[] = { &prm };
  hipLaunchCooperativeKernel((void*)fused_kernel, dim3(NGRID), dim3(NT),
                             args, 0, stream);
}

// Round 7
// 49372.263 us; speedup vs baseline: 1.0478x; 1.0478x over previous
//
#include <hip/hip_runtime.h>
#include <hip/hip_cooperative_groups.h>
#include <cstdint>
#include <cstddef>

namespace cg = cooperative_groups;

typedef _Float16 f16;
typedef _Float16 h2v __attribute__((ext_vector_type(2)));
typedef _Float16 h4v __attribute__((ext_vector_type(4)));
typedef _Float16 h8v __attribute__((ext_vector_type(8)));

static constexpr int BATCH = 128;
static constexpr int TSTEPS = 512;
static constexpr int NT = 256;
static constexpr int CK = 48;          // k-rows per staged chunk (12 KB f16)
static constexpr int NBAR = TSTEPS + 3;

// ---------------- workspace layout (byte offsets; identical for both configs) ----
static constexpr size_t B_XT  = 0;                               // f16 [512][64][128]
static constexpr size_t B_H1  = B_XT + 512ull * 64 * 128 * 2;
static constexpr size_t B_H2  = B_H1 + 2ull * 640 * 128 * 2;     // f16 parity pairs
static constexpr size_t B_H3  = B_H2 + 2ull * 400 * 128 * 2;
static constexpr size_t B_H4  = B_H3 + 2ull * 256 * 128 * 2;
static constexpr size_t B_HEND= B_H4 + 2ull * 256 * 128 * 2;
static constexpr size_t B_PK1 = B_HEND;                          // f32, H*K*4 each
static constexpr size_t B_PK2 = B_PK1 + 640ull * 704  * 4 * 4;
static constexpr size_t B_PK3 = B_PK2 + 400ull * 1040 * 4 * 4;
static constexpr size_t B_PK4 = B_PK3 + 256ull * 656  * 4 * 4;
static constexpr size_t B_BAR = B_PK4 + 256ull * 512  * 4 * 4;   // 8 KB barrier area
// U[0..511]: arrival slots; U[512 + g*64]: release lines g=0..15

struct KParams {
  const float *x;
  const float *k1, *r1, *b1, *k2, *r2, *b2, *k3, *r3, *b3, *k4, *r4, *b4;
  const float *wd1, *bd1, *wd2, *bd2, *wd3, *bd3, *wd4, *bd4, *wd5, *bd5, *wd6, *bd6;
  float *out;
  char *ws;
};

__device__ __forceinline__ void fma4(float4& a, float s, const float4& w) {
  a.x += s * w.x; a.y += s * w.y; a.z += s * w.z; a.w += s * w.w;
}
__device__ __forceinline__ float sigm(float v) { return 1.f / (1.f + expf(-v)); }

// ---- agent-scope (cross-XCD coherent) primitives ----
__device__ __forceinline__ uint64_t c_load8(const void* p) {
  return __hip_atomic_load((const uint64_t*)p, __ATOMIC_RELAXED, __HIP_MEMORY_SCOPE_AGENT);
}
__device__ __forceinline__ void c_store8(void* p, uint64_t v) {
  __hip_atomic_store((uint64_t*)p, v, __ATOMIC_RELAXED, __HIP_MEMORY_SCOPE_AGENT);
}
__device__ __forceinline__ void c_store4(void* p, unsigned v) {
  __hip_atomic_store((unsigned*)p, v, __ATOMIC_RELAXED, __HIP_MEMORY_SCOPE_AGENT);
}
__device__ __forceinline__ void c_store2(void* p, unsigned short v) {
  __hip_atomic_store((unsigned short*)p, v, __ATOMIC_RELAXED, __HIP_MEMORY_SCOPE_AGENT);
}
__device__ __forceinline__ unsigned short c_load2(const void* p) {
  return __hip_atomic_load((const unsigned short*)p, __ATOMIC_RELAXED, __HIP_MEMORY_SCOPE_AGENT);
}
__device__ __forceinline__ unsigned u_load(const unsigned* p) {
  return __hip_atomic_load(p, __ATOMIC_RELAXED, __HIP_MEMORY_SCOPE_AGENT);
}
__device__ __forceinline__ void u_store(unsigned* p, unsigned v) {
  __hip_atomic_store(p, v, __ATOMIC_RELAXED, __HIP_MEMORY_SCOPE_AGENT);
}

// ---- distributed barrier (arrival slots + master + spread release lines), busy-poll ----
__device__ __forceinline__ void light_barrier(unsigned* U, int bid, unsigned s1) {
  asm volatile("s_waitcnt vmcnt(0)" ::: "memory");   // h stores drained to coherence pt
  __syncthreads();
  if (threadIdx.x == 0) {
    u_store(&U[bid], s1);
    const unsigned* rel = &U[512 + (bid & 15) * 64];
    while (u_load(rel) < s1) {}
  }
  __syncthreads();
}

template<int TNB>
__device__ void master_role(unsigned* U) {
  const int tid = threadIdx.x;
  for (unsigned s1 = 1; s1 <= (unsigned)NBAR; ++s1) {
    for (;;) {
      bool ok = true;
      for (int i = tid; i < TNB; i += NT) ok &= (u_load(&U[i]) >= s1);
      if (__syncthreads_and((int)ok)) break;
    }
    if (tid < 16) u_store(&U[512 + tid * 64], s1);
  }
}

// ---------------- weight prepack: pack[blk][k][quad<NJ][gate] (f32) ----------------
__device__ void prepack_layer(const float* __restrict__ gk, const float* __restrict__ gr,
                              float* __restrict__ pack, int DIN, int H, int NJ, int NBLK,
                              int gtid, int gstr) {
  const long K = DIN + H;
  const long total = (long)NBLK * K * NJ * 4;
  for (long e = gtid; e < total; e += gstr) {
    int  g   = (int)(e & 3);
    long r   = e >> 2;
    int  q   = (int)(r % NJ);
    long r2  = r / NJ;
    int  k   = (int)(r2 % K);
    int  blk = (int)(r2 / K);
    int  j   = blk * NJ + q;
    float v = (k < DIN) ? gk[(size_t)k * 4 * H + (size_t)g * H + j]
                        : gr[(size_t)(k - DIN) * 4 * H + (size_t)g * H + j];
    pack[e] = v;
  }
}

// ---------------- persistent LSTM layer role (f16 exchange, chunked LDS dbuf) ----------------
template<int DIN, int H, int NJ, int LOFF, bool SEQIN>
__device__ __forceinline__ void lstm_role(int blk, int bid,
                          const f16* __restrict__ lo_base,   // xT (SEQIN) or lower-h parity pair
                          f16* __restrict__ ownH,
                          const float* __restrict__ pack,
                          const float* __restrict__ gbias,
                          char* smem, unsigned* U) {
  constexpr int K   = DIN + H;
  constexpr int BG  = NT / NJ;
  constexpr int MB  = BATCH / BG;                  // 1, 2 or 4
  constexpr int NCH = (K + CK - 1) / CK;
  constexpr int PPT = (CK * BATCH / 4) / NT;       // 6 x 8B units / thread / chunk
  static_assert(MB == 1 || MB == 2 || MB == 4, "MB");

  const int tid = threadIdx.x;
  const int jj  = tid / BG;
  const int bg  = tid % BG;
  const int b0  = bg * MB;
  const int j   = blk * NJ + jj;

  const float* mypack = pack + (size_t)blk * K * NJ * 4;
  const float4 bias = make_float4(gbias[j], gbias[H + j], gbias[2 * H + j], gbias[3 * H + j]);

  float c[MB];
  #pragma unroll
  for (int m = 0; m < MB; ++m) c[m] = 0.f;

  f16* buf0 = (f16*)smem;
  f16* buf1 = (f16*)(smem + CK * BATCH * 2);       // 12,288 B each

  for (int s = 0; s < NBAR; ++s) {
    const int t = s - LOFF;
    if (t >= 0 && t < TSTEPS) {
      const int par = (s - 1) & 1;
      const f16* src_lo = SEQIN ? (lo_base + (size_t)t * DIN * BATCH)
                                : (lo_base + (size_t)par * DIN * BATCH);
      const f16* src_hi = ownH + (size_t)par * H * BATCH;

      float4 a[MB];
      #pragma unroll
      for (int m = 0; m < MB; ++m) a[m] = make_float4(0.f, 0.f, 0.f, 0.f);

      // ---- stage chunk 0 (burst loads, then park) ----
      uint64_t tmp[PPT];
      #pragma unroll
      for (int r = 0; r < PPT; ++r) {
        const int p  = r * NT + tid;               // 8B unit; 32 units per 128-f16 row
        const int k  = p >> 5;
        const int bb = (p & 31) * 4;
        const f16* sp = (k < DIN) ? (src_lo + (size_t)k * BATCH + bb)
                                  : (src_hi + (size_t)(k - DIN) * BATCH + bb);
        tmp[r] = (SEQIN && k < DIN) ? *(const uint64_t*)sp : c_load8(sp);
      }
      #pragma unroll
      for (int r = 0; r < PPT; ++r) {
        const int p = r * NT + tid;
        *(uint64_t*)((char*)buf0 + 8 * p) = tmp[r];
      }
      __syncthreads();

      for (int ch = 0; ch < NCH; ++ch) {
        f16* cur = (ch & 1) ? buf1 : buf0;
        f16* nxt = (ch & 1) ? buf0 : buf1;
        const int kb = ch * CK;
        const bool more = (ch + 1 < NCH);

        if (more) {
          const int kb2 = kb + CK;
          #pragma unroll
          for (int r = 0; r < PPT; ++r) {
            const int p  = r * NT + tid;
            const int k  = kb2 + (p >> 5);
            const int bb = (p & 31) * 4;
            if (k < K) {
              const f16* sp = (k < DIN) ? (src_lo + (size_t)k * BATCH + bb)
                                        : (src_hi + (size_t)(k - DIN) * BATCH + bb);
              tmp[r] = (SEQIN && k < DIN) ? *(const uint64_t*)sp : c_load8(sp);
            } else tmp[r] = 0ull;
          }
        }

        const int kmax = (K - kb < CK) ? (K - kb) : CK;
        const float* wrow = mypack + ((size_t)kb * NJ + jj) * 4;
        #pragma unroll 4
        for (int kl = 0; kl < kmax; ++kl) {
          float4 w = *(const float4*)(wrow + (size_t)kl * NJ * 4);
          if constexpr (MB == 4) {
            h4v hv = *(const h4v*)(cur + kl * BATCH + b0);
            fma4(a[0], (float)hv.x, w); fma4(a[1], (float)hv.y, w);
            fma4(a[2], (float)hv.z, w); fma4(a[3], (float)hv.w, w);
          } else if constexpr (MB == 2) {
            h2v hv = *(const h2v*)(cur + kl * BATCH + b0);
            fma4(a[0], (float)hv.x, w); fma4(a[1], (float)hv.y, w);
          } else {
            fma4(a[0], (float)cur[kl * BATCH + b0], w);
          }
        }

        if (more) {
          #pragma unroll
          for (int r = 0; r < PPT; ++r) {
            const int p = r * NT + tid;
            *(uint64_t*)((char*)nxt + 8 * p) = tmp[r];
          }
        }
        __syncthreads();
      }

      // ---- epilogue: gates, state, coherent f16 store ----
      f16* dst = ownH + (size_t)(s & 1) * H * BATCH + (size_t)j * BATCH + b0;
      float hv[MB];
      #pragma unroll
      for (int m = 0; m < MB; ++m) {
        float ig = sigm(a[m].x + bias.x);
        float fg = sigm(a[m].y + bias.y);
        float gg = tanhf(a[m].z + bias.z);
        float og = sigm(a[m].w + bias.w);
        c[m] = fg * c[m] + ig * gg;
        hv[m] = og * tanhf(c[m]);
      }
      if constexpr (MB == 4) {
        union { f16 h[4]; uint64_t u; } o;
        o.h[0] = (f16)hv[0]; o.h[1] = (f16)hv[1]; o.h[2] = (f16)hv[2]; o.h[3] = (f16)hv[3];
        c_store8(dst, o.u);
      } else if constexpr (MB == 2) {
        union { f16 h[2]; unsigned u; } o;
        o.h[0] = (f16)hv[0]; o.h[1] = (f16)hv[1];
        c_store4(dst, o.u);
      } else {
        union { f16 h; unsigned short u; } o;
        o.h = (f16)hv[0];
        c_store2(dst, o.u);
      }
    }
    light_barrier(U, bid, (unsigned)(s + 1));
  }
}

// ---------------- dense head ----------------
__device__ void dense_stage(const float* in, float* outb,
                            const float* __restrict__ w, const float* __restrict__ bias,
                            int din, int dout, bool relu) {
  for (int jc = threadIdx.x; jc < dout; jc += NT) {
    float s = bias[jc];
    for (int d = 0; d < din; ++d) s += in[d] * w[(size_t)d * dout + jc];
    outb[jc] = relu ? fmaxf(s, 0.f) : s;
  }
  __syncthreads();
}

// ---------------- fused cooperative kernel (templated over block partition) ----------------
template<int TB1, int TB2, int TB3, int TB4>
__global__ __launch_bounds__(NT, 2) void fused_kernel(KParams p) {
  constexpr int TNB = TB1 + TB2 + TB3 + TB4;
  constexpr int NGRID = TNB + 1;
  constexpr int TRB2 = TB1, TRB3 = TB1 + TB2, TRB4 = TB1 + TB2 + TB3;
  constexpr int NJ1 = 640 / TB1, NJ2 = 400 / TB2, NJ3 = 256 / TB3, NJ4 = 256 / TB4;

  cg::grid_group grid = cg::this_grid();
  __shared__ __attribute__((aligned(16))) char smem[24576];   // 24 KB -> 2 blocks/CU

  char* ws = p.ws;
  unsigned* U = (unsigned*)(ws + B_BAR);
  const int tid  = threadIdx.x;
  const int bid  = blockIdx.x;
  const int gtid = bid * NT + tid;
  const int gstr = NGRID * NT;

  // ---- phase 0a: zero h parity buffers ----
  {
    uint64_t* hb = (uint64_t*)(ws + B_H1);
    const size_t n = (B_HEND - B_H1) / 8;
    for (size_t i = gtid; i < n; i += gstr) hb[i] = 0ull;
  }
  // ---- phase 0b: prepack weights (f32, per-block contiguous) ----
  prepack_layer(p.k1, p.r1, (float*)(ws + B_PK1), 64,  640, NJ1, TB1, gtid, gstr);
  prepack_layer(p.k2, p.r2, (float*)(ws + B_PK2), 640, 400, NJ2, TB2, gtid, gstr);
  prepack_layer(p.k3, p.r3, (float*)(ws + B_PK3), 400, 256, NJ3, TB3, gtid, gstr);
  prepack_layer(p.k4, p.r4, (float*)(ws + B_PK4), 256, 256, NJ4, TB4, gtid, gstr);
  // ---- phase 0c: transpose x [128][512][64] f32 -> xT [512][64][128] f16 ----
  {
    float* tile = (float*)smem;          // [32][129] f32 = 16,512 B
    f16* xT = (f16*)(ws + B_XT);
    for (int t = bid; t < TSTEPS; t += NGRID) {
      #pragma unroll
      for (int pass = 0; pass < 2; ++pass) {
        const int d0 = pass * 32;
        const int b = tid >> 1, half = tid & 1;
        const float* src = p.x + ((size_t)b * TSTEPS + t) * 64 + d0 + half * 16;
        float4 v[4];
        #pragma unroll
        for (int q = 0; q < 4; ++q) v[q] = *(const float4*)(src + 4 * q);
        __syncthreads();                 // prior pass readers done
        #pragma unroll
        for (int q = 0; q < 4; ++q) {
          tile[(half * 16 + 4 * q + 0) * 129 + b] = v[q].x;
          tile[(half * 16 + 4 * q + 1) * 129 + b] = v[q].y;
          tile[(half * 16 + 4 * q + 2) * 129 + b] = v[q].z;
          tile[(half * 16 + 4 * q + 3) * 129 + b] = v[q].w;
        }
        __syncthreads();
        const int r = tid >> 3, seg = tid & 7;
        f16* dst = xT + ((size_t)t * 64 + d0 + r) * BATCH + seg * 16;
        h8v o0, o1;
        #pragma unroll
        for (int i = 0; i < 8; ++i) {
          o0[i] = (f16)tile[r * 129 + seg * 16 + i];
          o1[i] = (f16)tile[r * 129 + seg * 16 + 8 + i];
        }
        *(h8v*)dst = o0;
        *(h8v*)(dst + 8) = o1;
      }
    }
  }

  // one full CG sync: publish xT/packs/zeroed-h device-wide (L2 writeback)
  grid.sync();

  // ---- phase 1: pipelined 4-layer LSTM scan ----
  if (bid == TNB) {
    master_role<TNB>(U);
  } else if (bid < TRB2) {
    lstm_role< 64, 640, NJ1, 0, true >(bid,        bid, (const f16*)(ws + B_XT),
                                       (f16*)(ws + B_H1), (const float*)(ws + B_PK1), p.b1, smem, U);
  } else if (bid < TRB3) {
    lstm_role<640, 400, NJ2, 1, false>(bid - TRB2, bid, (const f16*)(ws + B_H1),
                                       (f16*)(ws + B_H2), (const float*)(ws + B_PK2), p.b2, smem, U);
  } else if (bid < TRB4) {
    lstm_role<400, 256, NJ3, 2, false>(bid - TRB3, bid, (const f16*)(ws + B_H2),
                                       (f16*)(ws + B_H3), (const float*)(ws + B_PK3), p.b3, smem, U);
  } else {
    lstm_role<256, 256, NJ4, 3, false>(bid - TRB4, bid, (const f16*)(ws + B_H3),
                                       (f16*)(ws + B_H4), (const float*)(ws + B_PK4), p.b4, smem, U);
  }

  // ---- phase 2: dense head (h4 final = parity 0) ----
  if (bid < BATCH) {
    const int b = bid;
    float* A = (float*)smem;
    float* B = (float*)smem + 512;
    const f16* h4 = (const f16*)(ws + B_H4);
    for (int d = tid; d < 256; d += NT) {
      union { unsigned short u; f16 h; } cc;
      cc.u = c_load2(h4 + (size_t)d * BATCH + b);
      A[d] = (float)cc.h;
    }
    __syncthreads();
    dense_stage(A, B, p.wd1, p.bd1, 256, 512, true);
    dense_stage(B, A, p.wd2, p.bd2, 512, 256, true);
    dense_stage(A, B, p.wd3, p.bd3, 256, 128, true);
    dense_stage(B, A, p.wd4, p.bd4, 128, 64,  true);
    dense_stage(A, B, p.wd5, p.bd5, 64,  16,  true);
    dense_stage(B, A, p.wd6, p.bd6, 16,  3,   false);
    if (tid == 0) {
      float z0 = A[0], z1 = A[1], z2 = A[2];
      float m  = fmaxf(fmaxf(z0, z1), z2);
      float e0 = expf(z0 - m), e1 = expf(z1 - m), e2 = expf(z2 - m);
      float s  = e0 + e1 + e2;
      p.out[b * 3 + 0] = e0 / s;
      p.out[b * 3 + 1] = e1 / s;
      p.out[b * 3 + 2] = e2 / s;
    }
  }
}

// ---------------- launch: occupancy-validated config selection ----------------
extern "C" void kernel_launch(void* const* d_in, const int* in_sizes, int n_in,
                              void* d_out, int out_size, void* d_ws, size_t ws_size,
                              hipStream_t stream) {
  KParams prm;
  prm.x  = (const float*)d_in[0];
  prm.k1 = (const float*)d_in[1];  prm.r1 = (const float*)d_in[2];  prm.b1 = (const float*)d_in[3];
  prm.k2 = (const float*)d_in[4];  prm.r2 = (const float*)d_in[5];  prm.b2 = (const float*)d_in[6];
  prm.k3 = (const float*)d_in[7];  prm.r3 = (const float*)d_in[8];  prm.b3 = (const float*)d_in[9];
  prm.k4 = (const float*)d_in[10]; prm.r4 = (const float*)d_in[11]; prm.b4 = (const float*)d_in[12];
  prm.wd1 = (const float*)d_in[13]; prm.bd1 = (const float*)d_in[14];
  prm.wd2 = (const float*)d_in[15]; prm.bd2 = (const float*)d_in[16];
  prm.wd3 = (const float*)d_in[17]; prm.bd3 = (const float*)d_in[18];
  prm.wd4 = (const float*)d_in[19]; prm.bd4 = (const float*)d_in[20];
  prm.wd5 = (const float*)d_in[21]; prm.bd5 = (const float*)d_in[22];
  prm.wd6 = (const float*)d_in[23]; prm.bd6 = (const float*)d_in[24];
  prm.out = (float*)d_out;
  prm.ws  = (char*)d_ws;

  // zero barrier slots + release lines (ws re-poisoned 0xAA before every launch)
  hipMemsetAsync((char*)d_ws + B_BAR, 0, 8192, stream);

  // deterministic host-side occupancy query (not a stream op; graph-capture safe)
  int maxb = 0;
  hipOccupancyMaxActiveBlocksPerMultiprocessor(
      &maxb, (const void*)fused_kernel<160, 200, 64, 64>, NT, 0);

  void* args[] = { &prm };
  if (maxb >= 2) {
    hipLaunchCooperativeKernel((void*)fused_kernel<160, 200, 64, 64>,
                               dim3(489), dim3(NT), args, 0, stream);
  } else {
    hipLaunchCooperativeKernel((void*)fused_kernel<80, 100, 32, 32>,
                               dim3(245), dim3(NT), args, 0, stream);
  }
}